// Round 1
// baseline (902.655 us; speedup 1.0000x reference)
//
#include <hip/hip_runtime.h>
#include <stdint.h>

#define B 8192
#define T 512
#define K 24
#define LPB 12            // lanes per batch group (2 tag columns each)
#define GPB 16            // groups per block
#define BLK (LPB * GPB)   // 192 threads = 3 waves

// ---------------------------------------------------------------------------
// Forward Viterbi: alpha recurrence + backpointers.
// bp bytes for transition (t-1 -> t) are stored into d_out[b][t] bytes 72..95
// (floats 18..23 of the record); last_tag goes to d_out[b][0] bytes 72..75.
// Backward overwrites every record with the one-hot, so d_out ends clean.
// ---------------------------------------------------------------------------
__global__ __launch_bounds__(BLK) void crf_forward(
    const float* __restrict__ inp,    // [B, T, K]
    const float* __restrict__ trans,  // [K, K] (prev i -> cur j)
    float* __restrict__ out)          // [B, T, K] scratch/bp now, one-hot later
{
    __shared__ float alpha[2][GPB][K];   // double-buffered per-group alpha

    const int tid = threadIdx.x;
    const int g   = tid / LPB;
    const int l   = tid % LPB;
    const int b   = blockIdx.x * GPB + g;   // 512 blocks * 16 groups = 8192 exact
    const int j0  = 2 * l;                  // this lane's columns: j0, j0+1

    // Transition columns into registers (broadcast-friendly scalar loads).
    float tc0[K], tc1[K];
#pragma unroll
    for (int i = 0; i < K; ++i) {
        tc0[i] = trans[i * K + j0];
        tc1[i] = trans[i * K + j0 + 1];
    }

    const float* ebase = inp + (size_t)b * T * K;
    uint8_t*     obase = (uint8_t*)out + (size_t)b * T * K * 4;

    // t = 0: alpha = emissions[0]
    {
        float2 e0 = *(const float2*)(ebase + j0);
        alpha[0][g][j0]     = e0.x;
        alpha[0][g][j0 + 1] = e0.y;
    }
    __syncthreads();

    int cur = 0;
    for (int t = 1; t < T; ++t) {
        // emission for this step (independent of alpha -> overlaps LDS reads)
        float2 em = *(const float2*)(ebase + (size_t)t * K + j0);

        // read full alpha vector (broadcast within group)
        float a[K];
#pragma unroll
        for (int c = 0; c < 6; ++c) {
            float4 v = *(const float4*)&alpha[cur][g][4 * c];
            a[4 * c]     = v.x;
            a[4 * c + 1] = v.y;
            a[4 * c + 2] = v.z;
            a[4 * c + 3] = v.w;
        }

        // column j0: max_i (a[i] + tc0[i]), first-index tie-break
        float m0 = a[0] + tc0[0]; int p0 = 0;
#pragma unroll
        for (int i = 1; i < K; ++i) {
            float s = a[i] + tc0[i];
            bool gt = s > m0;
            m0 = gt ? s : m0;
            p0 = gt ? i : p0;
        }
        // column j0+1
        float m1 = a[0] + tc1[0]; int p1 = 0;
#pragma unroll
        for (int i = 1; i < K; ++i) {
            float s = a[i] + tc1[i];
            bool gt = s > m1;
            m1 = gt ? s : m1;
            p1 = gt ? i : p1;
        }

        float n0 = m0 + em.x;
        float n1 = m1 + em.y;
        alpha[cur ^ 1][g][j0]     = n0;
        alpha[cur ^ 1][g][j0 + 1] = n1;

        // backpointers (2 bytes per lane) into out[b][t] bytes 72 + 2l
        uint16_t bp2 = (uint16_t)((uint32_t)p0 | ((uint32_t)p1 << 8));
        *(uint16_t*)(obase + (size_t)t * 96 + 72 + 2 * l) = bp2;

        __syncthreads();
        cur ^= 1;
    }

    // last_tag = first-index argmax of final alpha; lane 0 of each group writes
    if (l == 0) {
        float m = alpha[cur][g][0]; int p = 0;
#pragma unroll
        for (int i = 1; i < K; ++i) {
            float v = alpha[cur][g][i];
            bool gt = v > m;
            m = gt ? v : m;
            p = gt ? i : p;
        }
        *(uint32_t*)(obase + 72) = (uint32_t)p;   // out[b][0] word 18
    }
}

// ---------------------------------------------------------------------------
// Backward: follow backpointers (prefetched 4 steps ahead) and write one-hot.
// All accesses via uint32 (1.0f == 0x3F800000) to keep aliasing well-defined.
// ---------------------------------------------------------------------------
__global__ __launch_bounds__(64) void crf_backward(float* __restrict__ outf)
{
    const int b = blockIdx.x * 64 + threadIdx.x;   // 128 blocks * 64 = 8192
    uint32_t* ob = (uint32_t*)outf + (size_t)b * T * K;

    int cur = (int)ob[18];   // last_tag stored at out[b][0] word 18

    // preload bp chunks for u = 511..508
    uint32_t w[4][6];
#pragma unroll
    for (int q = 0; q < 4; ++q) {
        const uint32_t* r = ob + (size_t)(511 - q) * K + 18;
#pragma unroll
        for (int c = 0; c < 6; ++c) w[q][c] = r[c];
    }

    for (int base = 511; base >= 1; base -= 4) {
        // prefetch the next 4 chunks (addresses independent of the tag chain)
        uint32_t nw[4][6];
#pragma unroll
        for (int q = 0; q < 4; ++q) {
            int u2 = base - 4 - q;
            if (u2 >= 1) {
                const uint32_t* r = ob + (size_t)u2 * K + 18;
#pragma unroll
                for (int c = 0; c < 6; ++c) nw[q][c] = r[c];
            }
        }

#pragma unroll
        for (int q = 0; q < 4; ++q) {
            int u = base - q;
            if (u >= 1) {
                uint32_t* rec = ob + (size_t)u * K;
                // one-hot for time u (tag = cur)
#pragma unroll
                for (int c = 0; c < 6; ++c) {
                    uint4 v;
                    v.x = (cur == 4 * c + 0) ? 0x3F800000u : 0u;
                    v.y = (cur == 4 * c + 1) ? 0x3F800000u : 0u;
                    v.z = (cur == 4 * c + 2) ? 0x3F800000u : 0u;
                    v.w = (cur == 4 * c + 3) ? 0x3F800000u : 0u;
                    *(uint4*)(rec + 4 * c) = v;
                }
                // next tag: byte `cur` of the 24-byte chunk
                int idx = cur >> 2;
                int sh  = (cur & 3) * 8;
                uint32_t wd = w[q][0];
                wd = (idx == 1) ? w[q][1] : wd;
                wd = (idx == 2) ? w[q][2] : wd;
                wd = (idx == 3) ? w[q][3] : wd;
                wd = (idx == 4) ? w[q][4] : wd;
                wd = (idx == 5) ? w[q][5] : wd;
                cur = (int)((wd >> sh) & 0xFF);
            }
        }

#pragma unroll
        for (int q = 0; q < 4; ++q)
#pragma unroll
            for (int c = 0; c < 6; ++c) w[q][c] = nw[q][c];
    }

    // u = 0: final tag
    {
#pragma unroll
        for (int c = 0; c < 6; ++c) {
            uint4 v;
            v.x = (cur == 4 * c + 0) ? 0x3F800000u : 0u;
            v.y = (cur == 4 * c + 1) ? 0x3F800000u : 0u;
            v.z = (cur == 4 * c + 2) ? 0x3F800000u : 0u;
            v.w = (cur == 4 * c + 3) ? 0x3F800000u : 0u;
            *(uint4*)(ob + 4 * c) = v;
        }
    }
}

extern "C" void kernel_launch(void* const* d_in, const int* in_sizes, int n_in,
                              void* d_out, int out_size, void* d_ws, size_t ws_size,
                              hipStream_t stream) {
    const float* inp   = (const float*)d_in[0];   // [8192, 512, 24]
    const float* trans = (const float*)d_in[1];   // [24, 24]
    float*       out   = (float*)d_out;           // [8192, 512, 24]

    crf_forward<<<B / GPB, BLK, 0, stream>>>(inp, trans, out);
    crf_backward<<<B / 64, 64, 0, stream>>>(out);
}